// Round 1
// baseline (561.057 us; speedup 1.0000x reference)
//
#include <hip/hip_runtime.h>

// CapsuleLayer: B=64, L=512, D=1024, C=32, O=64, 3 routing iters.
// Reformulated to avoid materializing u_hat (B,L,C,O):
//   s_j = x_c @ fc_w + csum * fc_b,   x_c[b,c,:] = sum_l c_ij[b,l,c] * in[b,l,:]
//   u_hat . v (for b_ij update) = in[b,l,:] @ w_v[b,:,c] + bias_v[b,c],
//   w_v[b,d,c] = sum_o fc_w[d, c*O+o] * v[b,c,o]
// Iter 0 has uniform c=1/32 -> s_0 from plain row-sum of inputs.

namespace {
constexpr int Bn = 64, Ln = 512, Dn = 1024, Cn = 32, On = 64, COn = Cn * On;
}

// ---------------------------------------------------------------- rowsum ----
__global__ __launch_bounds__(256) void k_rowsum(const float* __restrict__ in,
                                                float* __restrict__ rowsum) {
    int b = blockIdx.y;
    int d = blockIdx.x * 256 + threadIdx.x;
    const float* p = in + (size_t)b * Ln * Dn + d;
    float a0 = 0.f, a1 = 0.f, a2 = 0.f, a3 = 0.f;
    for (int l = 0; l < Ln; l += 4) {
        a0 += p[(size_t)(l + 0) * Dn];
        a1 += p[(size_t)(l + 1) * Dn];
        a2 += p[(size_t)(l + 2) * Dn];
        a3 += p[(size_t)(l + 3) * Dn];
    }
    rowsum[b * Dn + d] = (a0 + a1) + (a2 + a3);
}

// ------------------------------------------------------- s -> squash -> v ---
// mode0: x = rowsum[b,:] * (1/32), csum = 16 (iteration 0, uniform c).
// else : x = x_c[b,c,:], csum from k_xc.
// Also emits bias_v[b,c] = sum_o fc_b[c*O+o] * v[b,c,o] for the next pass.
__global__ __launch_bounds__(64) void k_sv(const float* __restrict__ xc,
                                           const float* __restrict__ csum,
                                           const float* __restrict__ fc_w,
                                           const float* __restrict__ fc_b,
                                           float* __restrict__ v_out,
                                           float* __restrict__ bias_v,
                                           int mode0) {
    int bc = blockIdx.x;           // b*32 + c
    int b = bc >> 5, c = bc & 31;
    int o = threadIdx.x;           // 0..63
    const float* x = mode0 ? (xc + (size_t)b * Dn) : (xc + (size_t)bc * Dn);
    const float* w = fc_w + c * On + o;
    float a0 = 0.f, a1 = 0.f, a2 = 0.f, a3 = 0.f;
    for (int k = 0; k < Dn; k += 4) {
        a0 += x[k + 0] * w[(size_t)(k + 0) * COn];
        a1 += x[k + 1] * w[(size_t)(k + 1) * COn];
        a2 += x[k + 2] * w[(size_t)(k + 2) * COn];
        a3 += x[k + 3] * w[(size_t)(k + 3) * COn];
    }
    float cs = mode0 ? 16.0f : csum[bc];
    float sc_in = mode0 ? (1.0f / 32.0f) : 1.0f;
    float s = sc_in * ((a0 + a1) + (a2 + a3)) + cs * fc_b[c * On + o];

    float sq = s * s;
#pragma unroll
    for (int off = 32; off > 0; off >>= 1) sq += __shfl_xor(sq, off, 64);
    float scale = sq / (1.0f + sq) * rsqrtf(sq + 1e-8f);
    float v = scale * s;
    v_out[(size_t)bc * On + o] = v;

    float bv = fc_b[c * On + o] * v;
#pragma unroll
    for (int off = 32; off > 0; off >>= 1) bv += __shfl_xor(bv, off, 64);
    if (o == 0) bias_v[bc] = bv;
}

// -------------------------------------------------- w_v[b,d,c] projection ---
// grid (8 dtiles, B), block 256 = 32 c x 8 dgroups; each thread 16 d's.
__global__ __launch_bounds__(256) void k_wv(const float* __restrict__ v,
                                            const float* __restrict__ fc_w,
                                            float* __restrict__ w_v) {
    int b = blockIdx.y;
    int c = threadIdx.x & 31, dg = threadIdx.x >> 5;
    __shared__ float v_sh[Cn * 65];  // stride 65 -> conflict-free reads
    for (int i = threadIdx.x; i < COn; i += 256) {
        int cc = i >> 6, oo = i & 63;
        v_sh[cc * 65 + oo] = v[(size_t)b * COn + i];
    }
    __syncthreads();
    const float* vc = v_sh + c * 65;
    int dbase = blockIdx.x * 128 + dg * 16;
    for (int i = 0; i < 16; ++i) {
        int d = dbase + i;
        const float4* wr = (const float4*)(fc_w + (size_t)d * COn + c * On);
        float acc = 0.f;
#pragma unroll
        for (int q = 0; q < 16; ++q) {
            float4 w4 = wr[q];
            acc += w4.x * vc[q * 4 + 0] + w4.y * vc[q * 4 + 1] +
                   w4.z * vc[q * 4 + 2] + w4.w * vc[q * 4 + 3];
        }
        w_v[((size_t)b * Dn + d) * Cn + c] = acc;
    }
}

// ------------------------------- dots -> b_ij update -> softmax -> c_w ------
// grid (4 ltiles, B), block 256: c8 = t&7 (c = c8*4+j), rg = t>>3 (0..31);
// rows = lt*128 + rg + 32*r (interleaved so ds_read_b128 is conflict-free).
__global__ __launch_bounds__(256) void k_route(const float* __restrict__ in,
                                               const float* __restrict__ w_v,
                                               const float* __restrict__ bias_v,
                                               float* __restrict__ b_ij,
                                               float* __restrict__ c_w,
                                               int first) {
    constexpr int ROWS = 128;
    constexpr int STR = 68;                  // float4-aligned padded stride
    __shared__ float in_sh[ROWS * STR];      // 34816 B
    __shared__ float w_sh[64 * Cn];          // 8192 B
    int b = blockIdx.y, lt = blockIdx.x;
    int t = threadIdx.x;
    int c8 = t & 7;
    int rg = t >> 3;
    int l0 = lt * ROWS;

    float acc[4][4];
#pragma unroll
    for (int r = 0; r < 4; ++r)
#pragma unroll
        for (int j = 0; j < 4; ++j) acc[r][j] = 0.f;

    for (int dt = 0; dt < 16; ++dt) {
        const float* gin = in + ((size_t)b * Ln + l0) * Dn + dt * 64;
#pragma unroll
        for (int i = 0; i < 8; ++i) {
            int fidx = t + 256 * i;   // 0..2047 float4 slots: 16 per row
            int row = fidx >> 4;
            int dq = fidx & 15;
            *(float4*)(in_sh + row * STR + dq * 4) =
                *(const float4*)(gin + (size_t)row * Dn + dq * 4);
        }
        const float* gw = w_v + ((size_t)b * Dn + dt * 64) * Cn;
#pragma unroll
        for (int i = 0; i < 2; ++i) {
            int fidx = t + 256 * i;   // 0..511
            *(float4*)(w_sh + fidx * 4) = *(const float4*)(gw + fidx * 4);
        }
        __syncthreads();
#pragma unroll 2
        for (int dd = 0; dd < 64; dd += 4) {
            float4 w0 = *(const float4*)(w_sh + (dd + 0) * Cn + c8 * 4);
            float4 w1 = *(const float4*)(w_sh + (dd + 1) * Cn + c8 * 4);
            float4 w2 = *(const float4*)(w_sh + (dd + 2) * Cn + c8 * 4);
            float4 w3 = *(const float4*)(w_sh + (dd + 3) * Cn + c8 * 4);
#pragma unroll
            for (int r = 0; r < 4; ++r) {
                float4 a = *(const float4*)(in_sh + (rg + 32 * r) * STR + dd);
                acc[r][0] += a.x * w0.x + a.y * w1.x + a.z * w2.x + a.w * w3.x;
                acc[r][1] += a.x * w0.y + a.y * w1.y + a.z * w2.y + a.w * w3.y;
                acc[r][2] += a.x * w0.z + a.y * w1.z + a.z * w2.z + a.w * w3.z;
                acc[r][3] += a.x * w0.w + a.y * w1.w + a.z * w2.w + a.w * w3.w;
            }
        }
        __syncthreads();
    }

    float4 bv = *(const float4*)(bias_v + b * Cn + c8 * 4);
#pragma unroll
    for (int r = 0; r < 4; ++r) {
        int row = l0 + rg + 32 * r;
        size_t boff = ((size_t)b * Ln + row) * Cn + c8 * 4;
        float4 bn;
        bn.x = acc[r][0] + bv.x;
        bn.y = acc[r][1] + bv.y;
        bn.z = acc[r][2] + bv.z;
        bn.w = acc[r][3] + bv.w;
        if (!first) {
            float4 bp = *(const float4*)(b_ij + boff);
            bn.x += bp.x; bn.y += bp.y; bn.z += bp.z; bn.w += bp.w;
        }
        *(float4*)(b_ij + boff) = bn;
        // softmax over 32 c's: 4 locals + xor-reduce over c8 lanes (bits 0..2)
        float m = fmaxf(fmaxf(bn.x, bn.y), fmaxf(bn.z, bn.w));
        m = fmaxf(m, __shfl_xor(m, 1, 64));
        m = fmaxf(m, __shfl_xor(m, 2, 64));
        m = fmaxf(m, __shfl_xor(m, 4, 64));
        float e0 = __expf(bn.x - m), e1 = __expf(bn.y - m),
              e2 = __expf(bn.z - m), e3 = __expf(bn.w - m);
        float sm = (e0 + e1) + (e2 + e3);
        sm += __shfl_xor(sm, 1, 64);
        sm += __shfl_xor(sm, 2, 64);
        sm += __shfl_xor(sm, 4, 64);
        float inv = 1.0f / sm;
        float4 cw = make_float4(e0 * inv, e1 * inv, e2 * inv, e3 * inv);
        *(float4*)(c_w + boff) = cw;
    }
}

// ----------------------------------------- x_c = c_w^T @ in  (+ csum) -------
// grid (8 dtiles, B), block 256: c8 = t&7 (4 c's), dg = t>>3 (4 d's);
// loops all L so no cross-block reduction; csum computed by dtile0/dg0 lanes.
__global__ __launch_bounds__(256) void k_xc(const float* __restrict__ in,
                                            const float* __restrict__ c_w,
                                            float* __restrict__ x_c,
                                            float* __restrict__ csum) {
    __shared__ float in_sh[64 * 128];  // 32 KB
    __shared__ float c_sh[64 * Cn];    // 8 KB
    int b = blockIdx.y, dtile = blockIdx.x;
    int t = threadIdx.x;
    int c8 = t & 7;
    int dg = t >> 3;
    float acc[4][4];
#pragma unroll
    for (int j = 0; j < 4; ++j)
#pragma unroll
        for (int k = 0; k < 4; ++k) acc[j][k] = 0.f;
    float cs0 = 0.f, cs1 = 0.f, cs2 = 0.f, cs3 = 0.f;
    const bool do_cs = (dtile == 0) && (dg == 0);

    for (int lc = 0; lc < 8; ++lc) {
        int l0 = lc * 64;
        const float* gin = in + ((size_t)b * Ln + l0) * Dn + dtile * 128;
#pragma unroll
        for (int i = 0; i < 8; ++i) {
            int fidx = t + 256 * i;   // 32 float4 per row
            int row = fidx >> 5;
            int dq = fidx & 31;
            *(float4*)(in_sh + row * 128 + dq * 4) =
                *(const float4*)(gin + (size_t)row * Dn + dq * 4);
        }
        const float* gc = c_w + ((size_t)b * Ln + l0) * Cn;
#pragma unroll
        for (int i = 0; i < 2; ++i) {
            int fidx = t + 256 * i;
            *(float4*)(c_sh + fidx * 4) = *(const float4*)(gc + fidx * 4);
        }
        __syncthreads();
#pragma unroll 2
        for (int l = 0; l < 64; ++l) {
            float4 c4 = *(const float4*)(c_sh + l * Cn + c8 * 4);
            float4 a4 = *(const float4*)(in_sh + l * 128 + dg * 4);
            acc[0][0] += c4.x * a4.x; acc[0][1] += c4.x * a4.y;
            acc[0][2] += c4.x * a4.z; acc[0][3] += c4.x * a4.w;
            acc[1][0] += c4.y * a4.x; acc[1][1] += c4.y * a4.y;
            acc[1][2] += c4.y * a4.z; acc[1][3] += c4.y * a4.w;
            acc[2][0] += c4.z * a4.x; acc[2][1] += c4.z * a4.y;
            acc[2][2] += c4.z * a4.z; acc[2][3] += c4.z * a4.w;
            acc[3][0] += c4.w * a4.x; acc[3][1] += c4.w * a4.y;
            acc[3][2] += c4.w * a4.z; acc[3][3] += c4.w * a4.w;
            if (do_cs) { cs0 += c4.x; cs1 += c4.y; cs2 += c4.z; cs3 += c4.w; }
        }
        __syncthreads();
    }
#pragma unroll
    for (int j = 0; j < 4; ++j) {
        int c = c8 * 4 + j;
        size_t off = ((size_t)b * Cn + c) * Dn + dtile * 128 + dg * 4;
        *(float4*)(x_c + off) = make_float4(acc[j][0], acc[j][1], acc[j][2], acc[j][3]);
    }
    if (do_cs) {
        int cb = b * Cn + c8 * 4;
        csum[cb + 0] = cs0; csum[cb + 1] = cs1;
        csum[cb + 2] = cs2; csum[cb + 3] = cs3;
    }
}

// ---------------------------------------------------------------------------
extern "C" void kernel_launch(void* const* d_in, const int* in_sizes, int n_in,
                              void* d_out, int out_size, void* d_ws, size_t ws_size,
                              hipStream_t stream) {
    const float* in   = (const float*)d_in[0];
    const float* fc_w = (const float*)d_in[1];
    const float* fc_b = (const float*)d_in[2];
    float* out = (float*)d_out;
    float* ws  = (float*)d_ws;

    // workspace layout (floats): total ~6.5M floats (~26 MB)
    float* rowsum = ws;                       // 64*1024          = 65536
    float* v      = rowsum + Bn * Dn;         // 64*32*64         = 131072
    float* bias_v = v + Bn * COn;             // 64*32            = 2048
    float* w_v    = bias_v + Bn * Cn;         // 64*1024*32       = 2097152
    float* b_ij   = w_v + (size_t)Bn * Dn * Cn;   // 64*512*32    = 1048576
    float* c_w    = b_ij + (size_t)Bn * Ln * Cn;  // 64*512*32    = 1048576
    float* x_c    = c_w + (size_t)Bn * Ln * Cn;   // 64*32*1024   = 2097152
    float* csum   = x_c + (size_t)Bn * Cn * Dn;   // 64*32        = 2048

    // iter 0 (uniform coupling): s0 from row-sums, v0, bias_v0
    k_rowsum<<<dim3(4, Bn), 256, 0, stream>>>(in, rowsum);
    k_sv<<<Bn * Cn, 64, 0, stream>>>(rowsum, nullptr, fc_w, fc_b, v, bias_v, 1);

    for (int t = 1; t <= 2; ++t) {
        k_wv<<<dim3(8, Bn), 256, 0, stream>>>(v, fc_w, w_v);
        k_route<<<dim3(4, Bn), 256, 0, stream>>>(in, w_v, bias_v, b_ij, c_w,
                                                 (t == 1) ? 1 : 0);
        k_xc<<<dim3(8, Bn), 256, 0, stream>>>(in, c_w, x_c, csum);
        float* vout = (t == 2) ? out : v;
        k_sv<<<Bn * Cn, 64, 0, stream>>>(x_c, csum, fc_w, fc_b, vout, bias_v, 0);
    }
}

// Round 2
// 505.022 us; speedup vs baseline: 1.1110x; 1.1110x over previous
//
#include <hip/hip_runtime.h>

// CapsuleLayer: B=64, L=512, D=1024, C=32, O=64, 3 routing iters.
// Reformulated to avoid materializing u_hat (B,L,C,O):
//   s_j = x_c @ fc_w + csum * fc_b,   x_c[b,c,:] = sum_l c_ij[b,l,c] * in[b,l,:]
//   u_hat . v (for b_ij update) = in[b,l,:] @ w_v[b,c,:] + bias_v[b,c],
//   w_v[b,c,d] = sum_o fc_w[d, c*O+o] * v[b,c,o]      (layout b,c,d!)
// Iter 0 has uniform c=1/32 -> s_0 from plain row-sum of inputs.

namespace {
constexpr int Bn = 64, Ln = 512, Dn = 1024, Cn = 32, On = 64, COn = Cn * On;
}

// ---------------------------------------------------------------- rowsum ----
__global__ __launch_bounds__(256) void k_rowsum(const float* __restrict__ in,
                                                float* __restrict__ rowsum) {
    int b = blockIdx.y;
    int d = blockIdx.x * 256 + threadIdx.x;
    const float* p = in + (size_t)b * Ln * Dn + d;
    float a0 = 0.f, a1 = 0.f, a2 = 0.f, a3 = 0.f;
    for (int l = 0; l < Ln; l += 4) {
        a0 += p[(size_t)(l + 0) * Dn];
        a1 += p[(size_t)(l + 1) * Dn];
        a2 += p[(size_t)(l + 2) * Dn];
        a3 += p[(size_t)(l + 3) * Dn];
    }
    rowsum[b * Dn + d] = (a0 + a1) + (a2 + a3);
}

// ------------------------------------------------------- s -> squash -> v ---
// Per-c GEMM: block c computes S[64 b][64 o] = X_c(64x1024) @ W_c(1024x64),
// then squash + v write + bias_v. mode0: X = rowsum/32 (same for all c), cs=16.
__global__ __launch_bounds__(256) void k_sv2(const float* __restrict__ xc,
                                             const float* __restrict__ csum,
                                             const float* __restrict__ fc_w,
                                             const float* __restrict__ fc_b,
                                             float* __restrict__ v_out,
                                             float* __restrict__ bias_v,
                                             int mode0) {
    int c = blockIdx.x;
    int t = threadIdx.x;
    int og = t & 15;    // o-quad: o = og*4 + oj
    int bg = t >> 4;    // b-quad: b = bg*4 + bi
    __shared__ float x_sh[64 * 68];   // 17408 B, stride 68 (16B aligned)
    __shared__ float w_sh[64 * 64];   // 16384 B  [d][o]
    float acc[4][4];
#pragma unroll
    for (int i = 0; i < 4; ++i)
#pragma unroll
        for (int j = 0; j < 4; ++j) acc[i][j] = 0.f;

    for (int kt = 0; kt < 16; ++kt) {
#pragma unroll
        for (int i = 0; i < 4; ++i) {
            int idx = t + 256 * i;        // 0..1023
            int bl = idx >> 4, dq = idx & 15;
            const float* src = mode0
                ? (xc + (size_t)bl * Dn + kt * 64 + dq * 4)
                : (xc + ((size_t)bl * Cn + c) * Dn + kt * 64 + dq * 4);
            *(float4*)(x_sh + bl * 68 + dq * 4) = *(const float4*)src;
        }
#pragma unroll
        for (int i = 0; i < 4; ++i) {
            int idx = t + 256 * i;
            int dl = idx >> 4, oq = idx & 15;
            *(float4*)(w_sh + dl * 64 + oq * 4) =
                *(const float4*)(fc_w + (size_t)(kt * 64 + dl) * COn + c * On + oq * 4);
        }
        __syncthreads();
#pragma unroll 2
        for (int d = 0; d < 64; d += 4) {
            float4 w4[4];
#pragma unroll
            for (int k = 0; k < 4; ++k)
                w4[k] = *(const float4*)(w_sh + (d + k) * 64 + og * 4);
#pragma unroll
            for (int bi = 0; bi < 4; ++bi) {
                float4 x4 = *(const float4*)(x_sh + (bg * 4 + bi) * 68 + d);
                acc[bi][0] += x4.x * w4[0].x + x4.y * w4[1].x + x4.z * w4[2].x + x4.w * w4[3].x;
                acc[bi][1] += x4.x * w4[0].y + x4.y * w4[1].y + x4.z * w4[2].y + x4.w * w4[3].y;
                acc[bi][2] += x4.x * w4[0].z + x4.y * w4[1].z + x4.z * w4[2].z + x4.w * w4[3].z;
                acc[bi][3] += x4.x * w4[0].w + x4.y * w4[1].w + x4.z * w4[2].w + x4.w * w4[3].w;
            }
        }
        __syncthreads();
    }

    int b0 = bg * 4;
    float4 fb = *(const float4*)(fc_b + c * On + og * 4);
    float sc_in = mode0 ? (1.0f / 32.0f) : 1.0f;
    float s[4][4], s2[4], bvp[4];
#pragma unroll
    for (int bi = 0; bi < 4; ++bi) {
        float cs = mode0 ? 16.0f : csum[(b0 + bi) * Cn + c];
        s[bi][0] = sc_in * acc[bi][0] + cs * fb.x;
        s[bi][1] = sc_in * acc[bi][1] + cs * fb.y;
        s[bi][2] = sc_in * acc[bi][2] + cs * fb.z;
        s[bi][3] = sc_in * acc[bi][3] + cs * fb.w;
        s2[bi] = s[bi][0] * s[bi][0] + s[bi][1] * s[bi][1] +
                 s[bi][2] * s[bi][2] + s[bi][3] * s[bi][3];
    }
#pragma unroll
    for (int off = 1; off <= 8; off <<= 1) {
#pragma unroll
        for (int bi = 0; bi < 4; ++bi) s2[bi] += __shfl_xor(s2[bi], off, 64);
    }
#pragma unroll
    for (int bi = 0; bi < 4; ++bi) {
        float sq = s2[bi];
        float scale = sq / (1.0f + sq) * rsqrtf(sq + 1e-8f);
        float4 vv = make_float4(scale * s[bi][0], scale * s[bi][1],
                                scale * s[bi][2], scale * s[bi][3]);
        *(float4*)(v_out + ((size_t)(b0 + bi) * Cn + c) * On + og * 4) = vv;
        bvp[bi] = fb.x * vv.x + fb.y * vv.y + fb.z * vv.z + fb.w * vv.w;
    }
#pragma unroll
    for (int off = 1; off <= 8; off <<= 1) {
#pragma unroll
        for (int bi = 0; bi < 4; ++bi) bvp[bi] += __shfl_xor(bvp[bi], off, 64);
    }
    if (og == 0) {
#pragma unroll
        for (int bi = 0; bi < 4; ++bi) bias_v[(b0 + bi) * Cn + c] = bvp[bi];
    }
}

// -------------------------------------------------- w_v[b,c,d] projection ---
// grid (8 dtiles, 32 c), block 256 = 8 bgroups x 32 dgroups.
// LDS-staged fc slab + v slab; thread computes 8b x 4d, float4-over-o inner.
__global__ __launch_bounds__(256) void k_wv2(const float* __restrict__ v,
                                             const float* __restrict__ fc_w,
                                             float* __restrict__ w_v) {
    int dtile = blockIdx.x;   // 0..7
    int c = blockIdx.y;       // 0..31
    int t = threadIdx.x;
    int bg = t & 7;           // b = bg + 8*bi
    int dg = t >> 3;          // d = d0 + dg*4 + dj
    __shared__ float fc_sh[128 * 68];  // 34816 B
    __shared__ float v_sh[64 * 68];    // 17408 B
    int d0 = dtile * 128;
#pragma unroll
    for (int i = 0; i < 8; ++i) {
        int idx = t + 256 * i;        // 0..2047 float4
        int dl = idx >> 4, oq = idx & 15;
        *(float4*)(fc_sh + dl * 68 + oq * 4) =
            *(const float4*)(fc_w + (size_t)(d0 + dl) * COn + c * On + oq * 4);
    }
#pragma unroll
    for (int i = 0; i < 4; ++i) {
        int idx = t + 256 * i;        // 0..1023
        int bl = idx >> 4, oq = idx & 15;
        *(float4*)(v_sh + bl * 68 + oq * 4) =
            *(const float4*)(v + ((size_t)bl * Cn + c) * On + oq * 4);
    }
    __syncthreads();

    float acc[8][4];
#pragma unroll
    for (int i = 0; i < 8; ++i)
#pragma unroll
        for (int j = 0; j < 4; ++j) acc[i][j] = 0.f;

#pragma unroll 2
    for (int o = 0; o < 64; o += 4) {
        float4 fc4[4];
#pragma unroll
        for (int dj = 0; dj < 4; ++dj)
            fc4[dj] = *(const float4*)(fc_sh + (dg * 4 + dj) * 68 + o);
#pragma unroll
        for (int bi = 0; bi < 8; ++bi) {
            float4 v4 = *(const float4*)(v_sh + (bg + 8 * bi) * 68 + o);
#pragma unroll
            for (int dj = 0; dj < 4; ++dj) {
                acc[bi][dj] += v4.x * fc4[dj].x + v4.y * fc4[dj].y +
                               v4.z * fc4[dj].z + v4.w * fc4[dj].w;
            }
        }
    }
#pragma unroll
    for (int bi = 0; bi < 8; ++bi) {
        int b = bg + 8 * bi;
        *(float4*)(w_v + ((size_t)b * Cn + c) * Dn + d0 + dg * 4) =
            make_float4(acc[bi][0], acc[bi][1], acc[bi][2], acc[bi][3]);
    }
}

// ------------------------------- dots -> b_ij update -> softmax -> c_w ------
// grid (4 ltiles, B), block 256: c8 = t&7 (c = c8*4+j), rg = t>>3 (0..31);
// rows = lt*128 + rg + 32*r (interleaved so ds_read_b128 is conflict-free).
// w_v layout is (b, c, d): w tile staged as w_sh[c][68-stride d].
__global__ __launch_bounds__(256) void k_route(const float* __restrict__ in,
                                               const float* __restrict__ w_v,
                                               const float* __restrict__ bias_v,
                                               float* __restrict__ b_ij,
                                               float* __restrict__ c_w,
                                               int first) {
    constexpr int ROWS = 128;
    constexpr int STR = 68;                  // float4-aligned padded stride
    __shared__ float in_sh[ROWS * STR];      // 34816 B
    __shared__ float w_sh[Cn * STR];         // 8704 B  [c][d]
    int b = blockIdx.y, lt = blockIdx.x;
    int t = threadIdx.x;
    int c8 = t & 7;
    int rg = t >> 3;
    int l0 = lt * ROWS;

    float acc[4][4];
#pragma unroll
    for (int r = 0; r < 4; ++r)
#pragma unroll
        for (int j = 0; j < 4; ++j) acc[r][j] = 0.f;

    for (int dt = 0; dt < 16; ++dt) {
        const float* gin = in + ((size_t)b * Ln + l0) * Dn + dt * 64;
#pragma unroll
        for (int i = 0; i < 8; ++i) {
            int fidx = t + 256 * i;   // 0..2047 float4 slots: 16 per row
            int row = fidx >> 4;
            int dq = fidx & 15;
            *(float4*)(in_sh + row * STR + dq * 4) =
                *(const float4*)(gin + (size_t)row * Dn + dq * 4);
        }
        const float* gw = w_v + (size_t)b * Cn * Dn + dt * 64;
#pragma unroll
        for (int i = 0; i < 2; ++i) {
            int idx = t + 256 * i;    // 0..511
            int cc = idx >> 4, dq = idx & 15;
            *(float4*)(w_sh + cc * STR + dq * 4) =
                *(const float4*)(gw + (size_t)cc * Dn + dq * 4);
        }
        __syncthreads();
#pragma unroll 2
        for (int dd = 0; dd < 64; dd += 4) {
            float4 wc[4];
#pragma unroll
            for (int j = 0; j < 4; ++j)
                wc[j] = *(const float4*)(w_sh + (c8 * 4 + j) * STR + dd);
#pragma unroll
            for (int r = 0; r < 4; ++r) {
                float4 a = *(const float4*)(in_sh + (rg + 32 * r) * STR + dd);
                acc[r][0] += a.x * wc[0].x + a.y * wc[0].y + a.z * wc[0].z + a.w * wc[0].w;
                acc[r][1] += a.x * wc[1].x + a.y * wc[1].y + a.z * wc[1].z + a.w * wc[1].w;
                acc[r][2] += a.x * wc[2].x + a.y * wc[2].y + a.z * wc[2].z + a.w * wc[2].w;
                acc[r][3] += a.x * wc[3].x + a.y * wc[3].y + a.z * wc[3].z + a.w * wc[3].w;
            }
        }
        __syncthreads();
    }

    float4 bv = *(const float4*)(bias_v + b * Cn + c8 * 4);
#pragma unroll
    for (int r = 0; r < 4; ++r) {
        int row = l0 + rg + 32 * r;
        size_t boff = ((size_t)b * Ln + row) * Cn + c8 * 4;
        float4 bn;
        bn.x = acc[r][0] + bv.x;
        bn.y = acc[r][1] + bv.y;
        bn.z = acc[r][2] + bv.z;
        bn.w = acc[r][3] + bv.w;
        if (!first) {
            float4 bp = *(const float4*)(b_ij + boff);
            bn.x += bp.x; bn.y += bp.y; bn.z += bp.z; bn.w += bp.w;
        }
        *(float4*)(b_ij + boff) = bn;
        // softmax over 32 c's: 4 locals + xor-reduce over c8 lanes (bits 0..2)
        float m = fmaxf(fmaxf(bn.x, bn.y), fmaxf(bn.z, bn.w));
        m = fmaxf(m, __shfl_xor(m, 1, 64));
        m = fmaxf(m, __shfl_xor(m, 2, 64));
        m = fmaxf(m, __shfl_xor(m, 4, 64));
        float e0 = __expf(bn.x - m), e1 = __expf(bn.y - m),
              e2 = __expf(bn.z - m), e3 = __expf(bn.w - m);
        float sm = (e0 + e1) + (e2 + e3);
        sm += __shfl_xor(sm, 1, 64);
        sm += __shfl_xor(sm, 2, 64);
        sm += __shfl_xor(sm, 4, 64);
        float inv = 1.0f / sm;
        float4 cw = make_float4(e0 * inv, e1 * inv, e2 * inv, e3 * inv);
        *(float4*)(c_w + boff) = cw;
    }
}

// ----------------------------------------- x_c = c_w^T @ in  (+ csum) -------
// grid (8 dtiles, B), block 256: c8 = t&7 (4 c's), dg = t>>3 (4 d's);
// loops all L so no cross-block reduction; csum computed by dtile0/dg0 lanes.
__global__ __launch_bounds__(256) void k_xc(const float* __restrict__ in,
                                            const float* __restrict__ c_w,
                                            float* __restrict__ x_c,
                                            float* __restrict__ csum) {
    __shared__ float in_sh[64 * 128];  // 32 KB
    __shared__ float c_sh[64 * Cn];    // 8 KB
    int b = blockIdx.y, dtile = blockIdx.x;
    int t = threadIdx.x;
    int c8 = t & 7;
    int dg = t >> 3;
    float acc[4][4];
#pragma unroll
    for (int j = 0; j < 4; ++j)
#pragma unroll
        for (int k = 0; k < 4; ++k) acc[j][k] = 0.f;
    float cs0 = 0.f, cs1 = 0.f, cs2 = 0.f, cs3 = 0.f;
    const bool do_cs = (dtile == 0) && (dg == 0);

    for (int lc = 0; lc < 8; ++lc) {
        int l0 = lc * 64;
        const float* gin = in + ((size_t)b * Ln + l0) * Dn + dtile * 128;
#pragma unroll
        for (int i = 0; i < 8; ++i) {
            int fidx = t + 256 * i;   // 32 float4 per row
            int row = fidx >> 5;
            int dq = fidx & 31;
            *(float4*)(in_sh + row * 128 + dq * 4) =
                *(const float4*)(gin + (size_t)row * Dn + dq * 4);
        }
        const float* gc = c_w + ((size_t)b * Ln + l0) * Cn;
#pragma unroll
        for (int i = 0; i < 2; ++i) {
            int fidx = t + 256 * i;
            *(float4*)(c_sh + fidx * 4) = *(const float4*)(gc + fidx * 4);
        }
        __syncthreads();
#pragma unroll 2
        for (int l = 0; l < 64; ++l) {
            float4 c4 = *(const float4*)(c_sh + l * Cn + c8 * 4);
            float4 a4 = *(const float4*)(in_sh + l * 128 + dg * 4);
            acc[0][0] += c4.x * a4.x; acc[0][1] += c4.x * a4.y;
            acc[0][2] += c4.x * a4.z; acc[0][3] += c4.x * a4.w;
            acc[1][0] += c4.y * a4.x; acc[1][1] += c4.y * a4.y;
            acc[1][2] += c4.y * a4.z; acc[1][3] += c4.y * a4.w;
            acc[2][0] += c4.z * a4.x; acc[2][1] += c4.z * a4.y;
            acc[2][2] += c4.z * a4.z; acc[2][3] += c4.z * a4.w;
            acc[3][0] += c4.w * a4.x; acc[3][1] += c4.w * a4.y;
            acc[3][2] += c4.w * a4.z; acc[3][3] += c4.w * a4.w;
            if (do_cs) { cs0 += c4.x; cs1 += c4.y; cs2 += c4.z; cs3 += c4.w; }
        }
        __syncthreads();
    }
#pragma unroll
    for (int j = 0; j < 4; ++j) {
        int c = c8 * 4 + j;
        size_t off = ((size_t)b * Cn + c) * Dn + dtile * 128 + dg * 4;
        *(float4*)(x_c + off) = make_float4(acc[j][0], acc[j][1], acc[j][2], acc[j][3]);
    }
    if (do_cs) {
        int cb = b * Cn + c8 * 4;
        csum[cb + 0] = cs0; csum[cb + 1] = cs1;
        csum[cb + 2] = cs2; csum[cb + 3] = cs3;
    }
}

// ---------------------------------------------------------------------------
extern "C" void kernel_launch(void* const* d_in, const int* in_sizes, int n_in,
                              void* d_out, int out_size, void* d_ws, size_t ws_size,
                              hipStream_t stream) {
    const float* in   = (const float*)d_in[0];
    const float* fc_w = (const float*)d_in[1];
    const float* fc_b = (const float*)d_in[2];
    float* out = (float*)d_out;
    float* ws  = (float*)d_ws;

    // workspace layout (floats): total ~6.5M floats (~26 MB)
    float* rowsum = ws;                       // 64*1024          = 65536
    float* v      = rowsum + Bn * Dn;         // 64*32*64         = 131072
    float* bias_v = v + Bn * COn;             // 64*32            = 2048
    float* w_v    = bias_v + Bn * Cn;         // 64*32*1024 (b,c,d) = 2097152
    float* b_ij   = w_v + (size_t)Bn * Dn * Cn;   // 64*512*32    = 1048576
    float* c_w    = b_ij + (size_t)Bn * Ln * Cn;  // 64*512*32    = 1048576
    float* x_c    = c_w + (size_t)Bn * Ln * Cn;   // 64*32*1024   = 2097152
    float* csum   = x_c + (size_t)Bn * Cn * Dn;   // 64*32        = 2048

    // iter 0 (uniform coupling): s0 from row-sums, v0, bias_v0
    k_rowsum<<<dim3(4, Bn), 256, 0, stream>>>(in, rowsum);
    k_sv2<<<Cn, 256, 0, stream>>>(rowsum, csum, fc_w, fc_b, v, bias_v, 1);

    for (int t = 1; t <= 2; ++t) {
        k_wv2<<<dim3(8, Cn), 256, 0, stream>>>(v, fc_w, w_v);
        k_route<<<dim3(4, Bn), 256, 0, stream>>>(in, w_v, bias_v, b_ij, c_w,
                                                 (t == 1) ? 1 : 0);
        k_xc<<<dim3(8, Bn), 256, 0, stream>>>(in, c_w, x_c, csum);
        float* vout = (t == 2) ? out : v;
        k_sv2<<<Cn, 256, 0, stream>>>(x_c, csum, fc_w, fc_b, vout, bias_v, 0);
    }
}

// Round 3
// 228.035 us; speedup vs baseline: 2.4604x; 2.2147x over previous
//
#include <hip/hip_runtime.h>

// CapsuleLayer: B=64, L=512, D=1024, C=32, O=64, 3 routing iters.
// u_hat never materialized:
//   dots[b,l,c] = in[b,l,:]@w_v[b,c,:] + bias_v[b,c]   (w_v[b,c,d] = sum_o fc_w[d,cO+o] v[b,c,o])
//   s_j[b,c,:]  = x_c[b,c,:]@fc_w[:,c,:] + csum[b,c]*fc_b[c,:]   (x_c = sum_l c_w * in)
// All three contractions via mfma_f32_16x16x32_bf16, no LDS staging (direct
// global->fragment loads; each operand row read once per wave, 64B coalesced).
// Layouts: in_T[b][d][l] bf16 (l-contig for xc B-frags), fc_wT[c*64+o][d] bf16,
// c_wT[b][c][l] bf16, x_cb[c][b][d] bf16, w_v[b][c][d] bf16.

namespace {
constexpr int Bn = 64, Ln = 512, Dn = 1024, Cn = 32, On = 64, COn = Cn * On;
}

typedef float f32x4 __attribute__((ext_vector_type(4)));
typedef short bf16x8 __attribute__((ext_vector_type(8)));

static __device__ __forceinline__ unsigned short f2bf(float f) {
    unsigned u = __float_as_uint(f);
    u += 0x7fff + ((u >> 16) & 1);   // RNE
    return (unsigned short)(u >> 16);
}

// ---------------------------------------------------------------- prep ------
// in fp32 [b][l][d]  ->  in_T bf16 [b][d][l]  +  rowsum partials [b][lc][d]
__global__ __launch_bounds__(256) void k_prep(const float* __restrict__ in,
                                              short* __restrict__ in_T,
                                              float* __restrict__ rs_p) {
    __shared__ short tr[64 * 260];      // [l-row][d-col], pad 260 shorts
    __shared__ float4 rs4_sh[4][64];
    int b = blockIdx.y;
    int lc = blockIdx.x >> 2, dc = blockIdx.x & 3;
    int t = threadIdx.x;
    int grp = t >> 6, dq = t & 63;
    float4 rs = make_float4(0.f, 0.f, 0.f, 0.f);
    const float* src = in + ((size_t)b * Ln + lc * 64) * Dn + dc * 256 + dq * 4;
#pragma unroll
    for (int i = 0; i < 16; ++i) {
        int row = grp + 4 * i;
        float4 x = *(const float4*)(src + (size_t)row * Dn);
        rs.x += x.x; rs.y += x.y; rs.z += x.z; rs.w += x.w;
        *(short4*)(&tr[row * 260 + dq * 4]) =
            make_short4((short)f2bf(x.x), (short)f2bf(x.y),
                        (short)f2bf(x.z), (short)f2bf(x.w));
    }
    rs4_sh[grp][dq] = rs;
    __syncthreads();
    if (t < 64) {
        float4 a = rs4_sh[0][t], b2 = rs4_sh[1][t], c2 = rs4_sh[2][t], d2 = rs4_sh[3][t];
        float4 s = make_float4(a.x + b2.x + c2.x + d2.x, a.y + b2.y + c2.y + d2.y,
                               a.z + b2.z + c2.z + d2.z, a.w + b2.w + c2.w + d2.w);
        *(float4*)(rs_p + ((size_t)b * 8 + lc) * Dn + dc * 256 + t * 4) = s;
    }
#pragma unroll
    for (int i = 0; i < 8; ++i) {
        int idx = t + 256 * i;
        int drow = idx >> 3, slot = idx & 7;
        bf16x8 v;
#pragma unroll
        for (int j = 0; j < 8; ++j) v[j] = tr[(slot * 8 + j) * 260 + drow];
        *(bf16x8*)(in_T + ((size_t)b * Dn + dc * 256 + drow) * Ln + lc * 64 + slot * 8) = v;
    }
}

// ---------------------------------------------------------------- wprep -----
// fc_w fp32 [d][co] -> fc_wT bf16 [co][d]
__global__ __launch_bounds__(256) void k_wprep(const float* __restrict__ fc_w,
                                               short* __restrict__ fc_wT) {
    __shared__ short tr[64 * 260];      // [d-row][co-col]
    int d0 = blockIdx.x * 64;           // 16
    int co0 = blockIdx.y * 256;         // 8
    int t = threadIdx.x, grp = t >> 6, cq = t & 63;
#pragma unroll
    for (int i = 0; i < 16; ++i) {
        int row = grp + 4 * i;
        float4 x = *(const float4*)(fc_w + (size_t)(d0 + row) * COn + co0 + cq * 4);
        *(short4*)(&tr[row * 260 + cq * 4]) =
            make_short4((short)f2bf(x.x), (short)f2bf(x.y),
                        (short)f2bf(x.z), (short)f2bf(x.w));
    }
    __syncthreads();
#pragma unroll
    for (int i = 0; i < 8; ++i) {
        int idx = t + 256 * i;
        int corow = idx >> 3, slot = idx & 7;
        bf16x8 v;
#pragma unroll
        for (int j = 0; j < 8; ++j) v[j] = tr[(slot * 8 + j) * 260 + corow];
        *(bf16x8*)(fc_wT + (size_t)(co0 + corow) * Dn + d0 + slot * 8) = v;
    }
}

// ---------------------------------------------------------------- rsred -----
__global__ __launch_bounds__(256) void k_rsred(const float* __restrict__ rs_p,
                                               unsigned short* __restrict__ rs_bf) {
    int b = blockIdx.y, d = blockIdx.x * 256 + threadIdx.x;
    float s = 0.f;
#pragma unroll
    for (int lc = 0; lc < 8; ++lc) s += rs_p[((size_t)b * 8 + lc) * Dn + d];
    rs_bf[b * Dn + d] = f2bf(s * (1.0f / 32.0f));
}

// ------------------------------------------------------- s -> squash -> v ---
// Per-c MFMA GEMM: S[64 b][64 o] = X(64x1024)@W_c(1024x64). No LDS.
__global__ __launch_bounds__(256) void k_sv3(const short* __restrict__ xA,
                                             const float* __restrict__ csum_p,
                                             const short* __restrict__ fc_wT,
                                             const float* __restrict__ fc_b,
                                             float* __restrict__ v_out,
                                             float* __restrict__ bias_v,
                                             int mode0) {
    int c = blockIdx.x;
    int t = threadIdx.x, w = t >> 6, lane = t & 63;
    int l15 = lane & 15, lg = lane >> 4;
    const short* A = mode0 ? xA : (xA + (size_t)c * Bn * Dn);   // [b][d]
    const short* Bw = fc_wT + (size_t)c * On * Dn;              // [o][d]
    f32x4 acc[4];
#pragma unroll
    for (int i = 0; i < 4; ++i) acc[i] = {0.f, 0.f, 0.f, 0.f};
    for (int ks = 0; ks < 32; ++ks) {
        int koff = ks * 32 + lg * 8;
        bf16x8 a = *(const bf16x8*)(A + (size_t)(w * 16 + l15) * Dn + koff);
#pragma unroll
        for (int dt = 0; dt < 4; ++dt) {
            bf16x8 bb = *(const bf16x8*)(Bw + (size_t)(dt * 16 + l15) * Dn + koff);
            acc[dt] = __builtin_amdgcn_mfma_f32_16x16x32_bf16(a, bb, acc[dt], 0, 0, 0);
        }
    }
    float fb[4];
#pragma unroll
    for (int dt = 0; dt < 4; ++dt) fb[dt] = fc_b[c * On + dt * 16 + l15];
#pragma unroll
    for (int r = 0; r < 4; ++r) {
        int brow = w * 16 + lg * 4 + r;
        float cs;
        if (mode0) {
            cs = 16.0f;
        } else {
            cs = 0.f;
#pragma unroll
            for (int lt = 0; lt < 8; ++lt) cs += csum_p[((size_t)lt * Bn + brow) * Cn + c];
        }
        float s0 = acc[0][r] + cs * fb[0];
        float s1 = acc[1][r] + cs * fb[1];
        float s2 = acc[2][r] + cs * fb[2];
        float s3 = acc[3][r] + cs * fb[3];
        float sq = s0 * s0 + s1 * s1 + s2 * s2 + s3 * s3;
        sq += __shfl_xor(sq, 1, 64); sq += __shfl_xor(sq, 2, 64);
        sq += __shfl_xor(sq, 4, 64); sq += __shfl_xor(sq, 8, 64);
        float scale = sq / (1.0f + sq) * rsqrtf(sq + 1e-8f);
        float v0 = scale * s0, v1 = scale * s1, v2 = scale * s2, v3 = scale * s3;
        float* vp = v_out + ((size_t)brow * Cn + c) * On;
        vp[0 * 16 + l15] = v0; vp[1 * 16 + l15] = v1;
        vp[2 * 16 + l15] = v2; vp[3 * 16 + l15] = v3;
        float bv = fb[0] * v0 + fb[1] * v1 + fb[2] * v2 + fb[3] * v3;
        bv += __shfl_xor(bv, 1, 64); bv += __shfl_xor(bv, 2, 64);
        bv += __shfl_xor(bv, 4, 64); bv += __shfl_xor(bv, 8, 64);
        if (l15 == 0) bias_v[brow * Cn + c] = bv;
    }
}

// -------------------------------------------------- w_v[b,c,d] projection ---
// fp32 math, bf16 output. grid (8 dtiles, 32 c), block 256.
__global__ __launch_bounds__(256) void k_wv2b(const float* __restrict__ v,
                                              const float* __restrict__ fc_w,
                                              short* __restrict__ w_vb) {
    int dtile = blockIdx.x;   // 0..7
    int c = blockIdx.y;       // 0..31
    int t = threadIdx.x;
    int bg = t & 7;           // b = bg + 8*bi
    int dg = t >> 3;          // d = d0 + dg*4 + dj
    __shared__ float fc_sh[128 * 68];
    __shared__ float v_sh[64 * 68];
    int d0 = dtile * 128;
#pragma unroll
    for (int i = 0; i < 8; ++i) {
        int idx = t + 256 * i;
        int dl = idx >> 4, oq = idx & 15;
        *(float4*)(fc_sh + dl * 68 + oq * 4) =
            *(const float4*)(fc_w + (size_t)(d0 + dl) * COn + c * On + oq * 4);
    }
#pragma unroll
    for (int i = 0; i < 4; ++i) {
        int idx = t + 256 * i;
        int bl = idx >> 4, oq = idx & 15;
        *(float4*)(v_sh + bl * 68 + oq * 4) =
            *(const float4*)(v + ((size_t)bl * Cn + c) * On + oq * 4);
    }
    __syncthreads();

    float acc[8][4];
#pragma unroll
    for (int i = 0; i < 8; ++i)
#pragma unroll
        for (int j = 0; j < 4; ++j) acc[i][j] = 0.f;

#pragma unroll 2
    for (int o = 0; o < 64; o += 4) {
        float4 fc4[4];
#pragma unroll
        for (int dj = 0; dj < 4; ++dj)
            fc4[dj] = *(const float4*)(fc_sh + (dg * 4 + dj) * 68 + o);
#pragma unroll
        for (int bi = 0; bi < 8; ++bi) {
            float4 v4 = *(const float4*)(v_sh + (bg + 8 * bi) * 68 + o);
#pragma unroll
            for (int dj = 0; dj < 4; ++dj) {
                acc[bi][dj] += v4.x * fc4[dj].x + v4.y * fc4[dj].y +
                               v4.z * fc4[dj].z + v4.w * fc4[dj].w;
            }
        }
    }
#pragma unroll
    for (int bi = 0; bi < 8; ++bi) {
        int b = bg + 8 * bi;
        *(short4*)(w_vb + ((size_t)b * Cn + c) * Dn + d0 + dg * 4) =
            make_short4((short)f2bf(acc[bi][0]), (short)f2bf(acc[bi][1]),
                        (short)f2bf(acc[bi][2]), (short)f2bf(acc[bi][3]));
    }
}

// ------------------------------- dots -> b_ij update -> softmax -> c_wT -----
// grid (8 lt, 64 b), 256 thr / 4 waves, wave = 16 l-rows x 32 c. MFMA, no
// LDS for operands (A built from fp32 input via cvt; B = w_v bf16 rows).
__global__ __launch_bounds__(256) void k_route_m(const float* __restrict__ in,
                                                 const short* __restrict__ w_v,
                                                 const float* __restrict__ bias_v,
                                                 float* __restrict__ b_ij,
                                                 short* __restrict__ c_wT,
                                                 float* __restrict__ csum_p,
                                                 int first) {
    __shared__ short cw_sh[Cn * 68];
    __shared__ float cs_sh[4][Cn];
    int lt = blockIdx.x, b = blockIdx.y;
    int t = threadIdx.x, w = t >> 6, lane = t & 63;
    int l15 = lane & 15, lg = lane >> 4;
    int l0 = lt * 64;
    f32x4 acc0 = {0.f, 0.f, 0.f, 0.f}, acc1 = {0.f, 0.f, 0.f, 0.f};
    const float* Ap = in + ((size_t)b * Ln + l0 + w * 16 + l15) * Dn;
    const short* Bp = w_v + (size_t)b * Cn * Dn;
    for (int ks = 0; ks < 32; ++ks) {
        int koff = ks * 32 + lg * 8;
        float4 xa = *(const float4*)(Ap + koff);
        float4 xb = *(const float4*)(Ap + koff + 4);
        bf16x8 a;
        a[0] = (short)f2bf(xa.x); a[1] = (short)f2bf(xa.y);
        a[2] = (short)f2bf(xa.z); a[3] = (short)f2bf(xa.w);
        a[4] = (short)f2bf(xb.x); a[5] = (short)f2bf(xb.y);
        a[6] = (short)f2bf(xb.z); a[7] = (short)f2bf(xb.w);
        bf16x8 b0 = *(const bf16x8*)(Bp + (size_t)l15 * Dn + koff);
        bf16x8 b1 = *(const bf16x8*)(Bp + (size_t)(l15 + 16) * Dn + koff);
        acc0 = __builtin_amdgcn_mfma_f32_16x16x32_bf16(a, b0, acc0, 0, 0, 0);
        acc1 = __builtin_amdgcn_mfma_f32_16x16x32_bf16(a, b1, acc1, 0, 0, 0);
    }
    float bv0 = bias_v[b * Cn + l15];
    float bv1 = bias_v[b * Cn + l15 + 16];
    float csa0 = 0.f, csa1 = 0.f;
#pragma unroll
    for (int r = 0; r < 4; ++r) {
        int lrow = l0 + w * 16 + lg * 4 + r;
        size_t boff = ((size_t)b * Ln + lrow) * Cn;
        float d0 = acc0[r] + bv0, d1 = acc1[r] + bv1;
        if (!first) { d0 += b_ij[boff + l15]; d1 += b_ij[boff + l15 + 16]; }
        b_ij[boff + l15] = d0;
        b_ij[boff + l15 + 16] = d1;
        float m = fmaxf(d0, d1);
        m = fmaxf(m, __shfl_xor(m, 1, 64)); m = fmaxf(m, __shfl_xor(m, 2, 64));
        m = fmaxf(m, __shfl_xor(m, 4, 64)); m = fmaxf(m, __shfl_xor(m, 8, 64));
        float e0 = __expf(d0 - m), e1 = __expf(d1 - m);
        float sm = e0 + e1;
        sm += __shfl_xor(sm, 1, 64); sm += __shfl_xor(sm, 2, 64);
        sm += __shfl_xor(sm, 4, 64); sm += __shfl_xor(sm, 8, 64);
        float inv = 1.0f / sm;
        float cw0 = e0 * inv, cw1 = e1 * inv;
        csa0 += cw0; csa1 += cw1;
        int ll = w * 16 + lg * 4 + r;
        cw_sh[l15 * 68 + ll] = (short)f2bf(cw0);
        cw_sh[(l15 + 16) * 68 + ll] = (short)f2bf(cw1);
    }
    csa0 += __shfl_xor(csa0, 16, 64); csa0 += __shfl_xor(csa0, 32, 64);
    csa1 += __shfl_xor(csa1, 16, 64); csa1 += __shfl_xor(csa1, 32, 64);
    if (lg == 0) { cs_sh[w][l15] = csa0; cs_sh[w][l15 + 16] = csa1; }
    __syncthreads();
    if (t < Cn) {
        float s = cs_sh[0][t] + cs_sh[1][t] + cs_sh[2][t] + cs_sh[3][t];
        csum_p[((size_t)lt * Bn + b) * Cn + t] = s;
    }
    {
        int cc = t >> 3, slot = t & 7;
        bf16x8 vv;
#pragma unroll
        for (int j = 0; j < 8; ++j) vv[j] = cw_sh[cc * 68 + slot * 8 + j];
        *(bf16x8*)(c_wT + ((size_t)b * Cn + cc) * Ln + l0 + slot * 8) = vv;
    }
}

// ----------------------------------------- x_cb[c][b][d] = c_w^T @ in -------
// grid (4 dt, 64 b), 256 thr / 4 waves; contraction over l via in_T[b][d][l].
__global__ __launch_bounds__(256) void k_xc_m(const short* __restrict__ in_T,
                                              const short* __restrict__ c_wT,
                                              short* __restrict__ x_cb) {
    int dt = blockIdx.x, b = blockIdx.y;
    int t = threadIdx.x, w = t >> 6, lane = t & 63;
    int l15 = lane & 15, lg = lane >> 4;
    f32x4 acc[2][4];
#pragma unroll
    for (int h = 0; h < 2; ++h)
#pragma unroll
        for (int dd = 0; dd < 4; ++dd) acc[h][dd] = {0.f, 0.f, 0.f, 0.f};
    const short* A = c_wT + (size_t)b * Cn * Ln;                       // [c][l]
    const short* Bp = in_T + ((size_t)b * Dn + dt * 256 + w * 64) * Ln; // [d][l]
    for (int ks = 0; ks < 16; ++ks) {
        int koff = ks * 32 + lg * 8;
        bf16x8 a0 = *(const bf16x8*)(A + (size_t)l15 * Ln + koff);
        bf16x8 a1 = *(const bf16x8*)(A + (size_t)(l15 + 16) * Ln + koff);
#pragma unroll
        for (int dd = 0; dd < 4; ++dd) {
            bf16x8 bb = *(const bf16x8*)(Bp + (size_t)(dd * 16 + l15) * Ln + koff);
            acc[0][dd] = __builtin_amdgcn_mfma_f32_16x16x32_bf16(a0, bb, acc[0][dd], 0, 0, 0);
            acc[1][dd] = __builtin_amdgcn_mfma_f32_16x16x32_bf16(a1, bb, acc[1][dd], 0, 0, 0);
        }
    }
#pragma unroll
    for (int h = 0; h < 2; ++h)
#pragma unroll
        for (int dd = 0; dd < 4; ++dd)
#pragma unroll
            for (int r = 0; r < 4; ++r) {
                int c = 16 * h + lg * 4 + r;
                int d = dt * 256 + w * 64 + dd * 16 + l15;
                x_cb[((size_t)c * Bn + b) * Dn + d] = (short)f2bf(acc[h][dd][r]);
            }
}

// ---------------------------------------------------------------------------
extern "C" void kernel_launch(void* const* d_in, const int* in_sizes, int n_in,
                              void* d_out, int out_size, void* d_ws, size_t ws_size,
                              hipStream_t stream) {
    const float* in   = (const float*)d_in[0];
    const float* fc_w = (const float*)d_in[1];
    const float* fc_b = (const float*)d_in[2];
    float* out = (float*)d_out;

    char* p = (char*)d_ws;
    auto alloc = [&](size_t bytes) -> char* {
        char* r = p;
        p += (bytes + 255) & ~(size_t)255;
        return r;
    };
    short* in_T   = (short*)alloc((size_t)Bn * Dn * Ln * 2);   // 64 MB
    short* fc_wT  = (short*)alloc((size_t)COn * Dn * 2);       // 4 MB
    short* w_vb   = (short*)alloc((size_t)Bn * Cn * Dn * 2);   // 4 MB
    short* c_wT   = (short*)alloc((size_t)Bn * Cn * Ln * 2);   // 2 MB
    short* x_cb   = (short*)alloc((size_t)Cn * Bn * Dn * 2);   // 4 MB
    float* rs_p   = (float*)alloc((size_t)Bn * 8 * Dn * 4);    // 2 MB
    unsigned short* rs_bf = (unsigned short*)alloc((size_t)Bn * Dn * 2);
    float* b_ij   = (float*)alloc((size_t)Bn * Ln * Cn * 4);   // 4 MB
    float* v      = (float*)alloc((size_t)Bn * Cn * On * 4);
    float* bias_v = (float*)alloc((size_t)Bn * Cn * 4);
    float* csum_p = (float*)alloc((size_t)8 * Bn * Cn * 4);

    k_prep<<<dim3(32, Bn), 256, 0, stream>>>(in, in_T, rs_p);
    k_wprep<<<dim3(16, 8), 256, 0, stream>>>(fc_w, fc_wT);
    k_rsred<<<dim3(4, Bn), 256, 0, stream>>>(rs_p, rs_bf);
    k_sv3<<<Cn, 256, 0, stream>>>((const short*)rs_bf, csum_p, fc_wT, fc_b,
                                  v, bias_v, 1);
    for (int it = 1; it <= 2; ++it) {
        k_wv2b<<<dim3(8, Cn), 256, 0, stream>>>(v, fc_w, w_vb);
        k_route_m<<<dim3(8, Bn), 256, 0, stream>>>(in, w_vb, bias_v, b_ij,
                                                   c_wT, csum_p, (it == 1) ? 1 : 0);
        k_xc_m<<<dim3(4, Bn), 256, 0, stream>>>(in_T, c_wT, x_cb);
        float* vout = (it == 2) ? out : v;
        k_sv3<<<Cn, 256, 0, stream>>>(x_cb, csum_p, fc_wT, fc_b, vout, bias_v, 0);
    }
}